// Round 1
// baseline (7256.738 us; speedup 1.0000x reference)
//
#include <hip/hip_runtime.h>

#define TT 512
#define BB 32
#define DD 1024
#define UU 1024
#define LL 16
#define GG 4128
#define NBLK 129
#define GPAD 4224

typedef _Float16 f16;
typedef _Float16 half8 __attribute__((ext_vector_type(8)));
typedef _Float16 half4 __attribute__((ext_vector_type(4)));
typedef float f32x4 __attribute__((ext_vector_type(4)));

// ---------------- transpose + f32->f16 convert: in[R][C] f32 -> out[C][R] f16 ----
__global__ void k_transpose_cvt(const float* __restrict__ in, f16* __restrict__ out,
                                int R, int C) {
  __shared__ float tile[32][33];
  int bx = blockIdx.x * 32, by = blockIdx.y * 32;
  int tx = threadIdx.x & 31, ty = threadIdx.x >> 5;
#pragma unroll
  for (int j = 0; j < 4; ++j) {
    int r = by + ty + j * 8;
    tile[ty + j * 8][tx] = in[(long)r * C + bx + tx];
  }
  __syncthreads();
#pragma unroll
  for (int j = 0; j < 4; ++j) {
    int c = bx + ty + j * 8;
    out[(long)c * R + by + tx] = (f16)tile[tx][ty + j * 8];
  }
}

// ---------------- phase 1: Zx[m][n] = (f16)(X[m][:] @ W[:][n] + bias[n]) ----------
// X: [16384][1024] f32 (read directly, converted to f16 during staging)
// Bt: [GPAD][1024] f16 = W^T (pad rows zeroed)
__global__ __launch_bounds__(256) void k_gemm_xw(
    const float* __restrict__ X,
    const f16* __restrict__ Bt,
    const float* __restrict__ bias,
    f16* __restrict__ Zx) {
  __shared__ f16 As[128 * 32];
  __shared__ f16 Bs[128 * 32];
  const int m0 = blockIdx.x * 128;
  const int n0 = blockIdx.y * 128;
  const int tid = threadIdx.x;
  const int wave = tid >> 6, lane = tid & 63;
  const int mrow = (wave & 1) * 64, ncol = (wave >> 1) * 64;
  f32x4 acc[4][4];
#pragma unroll
  for (int i = 0; i < 4; ++i)
#pragma unroll
    for (int j = 0; j < 4; ++j)
      acc[i][j] = (f32x4){0.f, 0.f, 0.f, 0.f};

  float4 ra[4];
  uint4 rb[2];
  auto load_tiles = [&](int k0) {
#pragma unroll
    for (int q = 0; q < 4; ++q) {
      int flat = q * 256 + tid;
      int r = flat >> 3, s = flat & 7;
      ra[q] = *(const float4*)(X + (long)(m0 + r) * 1024 + k0 + s * 4);
    }
#pragma unroll
    for (int q = 0; q < 2; ++q) {
      int flat = q * 256 + tid;
      int r = flat >> 2, s = flat & 3;
      rb[q] = *(const uint4*)(Bt + (long)(n0 + r) * 1024 + k0 + s * 8);
    }
  };
  load_tiles(0);
  for (int kt = 0; kt < 32; ++kt) {
    __syncthreads();
#pragma unroll
    for (int q = 0; q < 4; ++q) {
      int flat = q * 256 + tid;
      half4 h;
      h[0] = (f16)ra[q].x; h[1] = (f16)ra[q].y;
      h[2] = (f16)ra[q].z; h[3] = (f16)ra[q].w;
      *(half4*)((char*)As + flat * 8) = h;
    }
#pragma unroll
    for (int q = 0; q < 2; ++q) {
      int flat = q * 256 + tid;
      *(uint4*)((char*)Bs + flat * 16) = rb[q];
    }
    __syncthreads();
    if (kt + 1 < 32) load_tiles((kt + 1) * 32);
    const int kseg2 = ((lane >> 4) * 8) * 2;  // byte offset of this lane's k-seg
    half8 af[4], bf[4];
#pragma unroll
    for (int i = 0; i < 4; ++i) {
      int r = mrow + i * 16 + (lane & 15);
      af[i] = *(const half8*)((const char*)As + r * 64 + kseg2);
      int c = ncol + i * 16 + (lane & 15);
      bf[i] = *(const half8*)((const char*)Bs + c * 64 + kseg2);
    }
#pragma unroll
    for (int i = 0; i < 4; ++i)
#pragma unroll
      for (int j = 0; j < 4; ++j)
        acc[i][j] = __builtin_amdgcn_mfma_f32_16x16x32_f16(af[i], bf[j], acc[i][j], 0, 0, 0);
  }
#pragma unroll
  for (int j = 0; j < 4; ++j) {
    int n = n0 + ncol + j * 16 + (lane & 15);
    if (n < GG) {
      float bv = bias[n];
#pragma unroll
      for (int i = 0; i < 4; ++i) {
#pragma unroll
        for (int r = 0; r < 4; ++r) {
          int m = m0 + mrow + i * 16 + (lane >> 4) * 4 + r;
          Zx[(long)m * GG + n] = (f16)(acc[i][j][r] + bv);
        }
      }
    }
  }
}

// ---------------- phase 2 helpers ----------------
__device__ __forceinline__ void grid_bar(unsigned* cnt, unsigned idx) {
  // all cross-block data uses agent-scope (L2-bypassing) accesses, so release
  // ordering only needs the vm queue drained; no L2 writeback/invalidate.
  asm volatile("s_waitcnt vmcnt(0)" ::: "memory");
  __syncthreads();
  if (threadIdx.x == 0) {
    __hip_atomic_fetch_add(cnt, 1u, __ATOMIC_RELAXED, __HIP_MEMORY_SCOPE_AGENT);
    const unsigned target = idx * (unsigned)NBLK;
    while (__hip_atomic_load(cnt, __ATOMIC_RELAXED, __HIP_MEMORY_SCOPE_AGENT) < target) {
      __builtin_amdgcn_s_sleep(1);
    }
  }
  __syncthreads();
}

__device__ __forceinline__ float sigm(float x) { return 1.f / (1.f + __expf(-x)); }
__device__ __forceinline__ float tanh_(float x) {
  float ax = fabsf(x);
  float e = __expf(-2.f * ax);
  float t = (1.f - e) / (1.f + e);
  return copysignf(t, x);
}
__device__ __forceinline__ void ld4(const float* p, float* o) {
  unsigned long long* q = (unsigned long long*)p;
  unsigned long long a = __hip_atomic_load(q, __ATOMIC_RELAXED, __HIP_MEMORY_SCOPE_AGENT);
  unsigned long long b = __hip_atomic_load(q + 1, __ATOMIC_RELAXED, __HIP_MEMORY_SCOPE_AGENT);
  o[0] = __uint_as_float((unsigned)a);
  o[1] = __uint_as_float((unsigned)(a >> 32));
  o[2] = __uint_as_float((unsigned)b);
  o[3] = __uint_as_float((unsigned)(b >> 32));
}

// ---------------- phase 2: persistent recurrent kernel ----------------
// grid = 129 blocks x 256 threads. Block g owns z columns [g*32, g*32+32).
// LDS: [0,64K)   = R^T slab, swizzled 16B chunks (resident all steps)
//      [64K,128K)= h staging (per step)
//      [128K,..) = 64 floats for cumsoftmax masters
__global__ __launch_bounds__(256, 1) void k_onlstm(
    const f16* __restrict__ Zx,               // [16384][GG] f16
    const f16* __restrict__ Rt,               // [GG][1024] f16
    unsigned long long* __restrict__ hbuf,    // [32][1024] f16 as ull[8192]
    float* __restrict__ zbuf,                 // [32][GG] f32
    float* __restrict__ Y,                    // [32][512][1024] f32
    unsigned* __restrict__ cnt) {
  extern __shared__ char lds[];
  const int g = blockIdx.x;
  const int g0 = g * 32;
  const int tid = threadIdx.x;
  const int wave = tid >> 6, lane = tid & 63;
  const int mt = wave & 1, nt = wave >> 1;

  // load R^T slab (32 cols x 1024 k, f16) into LDS, swizzled
#pragma unroll
  for (int it = 0; it < 16; ++it) {
    int idx = it * 256 + tid;
    int c = idx >> 7, chunk = idx & 127;
    uint4 v = *(const uint4*)(Rt + (long)(g0 + c) * 1024 + chunk * 8);
    int off16 = c * 128 + (chunk ^ (c & 7));
    *(uint4*)(lds + off16 * 16) = v;
  }

  float creg[4] = {0.f, 0.f, 0.f, 0.f};
  const int lgate = tid >> 4;        // level 0..15
  const int c0 = (tid & 15) * 4;     // chunk offset 0..60
  float* zm = (float*)(lds + 131072);
  float* cumf = zm + 32;
  float* cumi = zm + 48;

  __syncthreads();
  unsigned bar = 0;

  const int n_loc = nt * 16 + (lane & 15);
  const int n_gl = g0 + n_loc;
  const int q4 = lane >> 4;
  const int ar = mt * 16 + (lane & 15);
  const int br = n_loc;

  for (int t = 0; t < TT; ++t) {
    // prefetch Zx values matching this lane's C-frag (plain cached; immutable)
    f16 zx[4];
#pragma unroll
    for (int r = 0; r < 4; ++r) {
      int b = mt * 16 + q4 * 4 + r;
      zx[r] = Zx[((long)b * TT + t) * GG + n_gl];
    }
    // stage h -> LDS (agent-scope loads bypass possibly-stale L2)
#pragma unroll
    for (int it = 0; it < 16; ++it) {
      int idx = it * 256 + tid;
      int r = idx >> 7, chunk = idx & 127;
      unsigned long long lo = __hip_atomic_load(hbuf + idx * 2, __ATOMIC_RELAXED, __HIP_MEMORY_SCOPE_AGENT);
      unsigned long long hi = __hip_atomic_load(hbuf + idx * 2 + 1, __ATOMIC_RELAXED, __HIP_MEMORY_SCOPE_AGENT);
      int off16 = 4096 + r * 128 + (chunk ^ (r & 7));
      uint4 v;
      v.x = (unsigned)lo; v.y = (unsigned)(lo >> 32);
      v.z = (unsigned)hi; v.w = (unsigned)(hi >> 32);
      *(uint4*)(lds + off16 * 16) = v;
    }
    __syncthreads();
    // z[b][n] = h @ R  (+ Zx)
    f32x4 acc0 = {0.f, 0.f, 0.f, 0.f}, acc1 = {0.f, 0.f, 0.f, 0.f};
#pragma unroll 8
    for (int kk = 0; kk < 32; kk += 2) {
      int ch0 = kk * 4 + q4;
      int ch1 = ch0 + 4;
      half8 a0 = *(const half8*)(lds + (4096 + ar * 128 + (ch0 ^ (ar & 7))) * 16);
      half8 b0 = *(const half8*)(lds + (br * 128 + (ch0 ^ (br & 7))) * 16);
      half8 a1 = *(const half8*)(lds + (4096 + ar * 128 + (ch1 ^ (ar & 7))) * 16);
      half8 b1 = *(const half8*)(lds + (br * 128 + (ch1 ^ (br & 7))) * 16);
      acc0 = __builtin_amdgcn_mfma_f32_16x16x32_f16(a0, b0, acc0, 0, 0, 0);
      acc1 = __builtin_amdgcn_mfma_f32_16x16x32_f16(a1, b1, acc1, 0, 0, 0);
    }
#pragma unroll
    for (int r = 0; r < 4; ++r) {
      int b = mt * 16 + q4 * 4 + r;
      float zv = acc0[r] + acc1[r] + (float)zx[r];
      __hip_atomic_store(zbuf + (long)b * GG + n_gl, zv, __ATOMIC_RELAXED, __HIP_MEMORY_SCOPE_AGENT);
    }
    ++bar;
    grid_bar(cnt, bar);

    // ---- gate phase: blocks 0..31, block g == batch b ----
    if (g < 32) {
      const float* zrow = zbuf + (long)g * GG;
      if (tid < 16) {
        unsigned long long v = __hip_atomic_load((unsigned long long*)zrow + tid, __ATOMIC_RELAXED, __HIP_MEMORY_SCOPE_AGENT);
        zm[tid * 2] = __uint_as_float((unsigned)v);
        zm[tid * 2 + 1] = __uint_as_float((unsigned)(v >> 32));
      }
      __syncthreads();
      if (tid < 32) {
        const float* zz = zm + (tid & 16);
        int l = tid & 15;
        float mx = zz[0];
#pragma unroll
        for (int j = 1; j < 16; ++j) mx = fmaxf(mx, zz[j]);
        float s = 0.f, p = 0.f;
#pragma unroll
        for (int j = 0; j < 16; ++j) {
          float e = __expf(zz[j] - mx);
          s += e;
          if (tid < 16) { if (j <= l) p += e; }
          else          { if (j >= l) p += e; }
        }
        if (tid < 16) cumf[l] = p / s;
        else          cumi[l] = p / s;
      }
      __syncthreads();
      const float fm = cumf[lgate], im = cumi[lgate];
      const float ov = fm * im;
      float zf[4], zi[4], zo[4], zc[4];
      ld4(zrow + 32 + 0 * 1024 + lgate * 64 + c0, zf);
      ld4(zrow + 32 + 1 * 1024 + lgate * 64 + c0, zi);
      ld4(zrow + 32 + 2 * 1024 + lgate * 64 + c0, zo);
      ld4(zrow + 32 + 3 * 1024 + lgate * 64 + c0, zc);
      float ho[4];
#pragma unroll
      for (int j = 0; j < 4; ++j) {
        float f = sigm(zf[j]), i = sigm(zi[j]), o = sigm(zo[j]);
        float ci = tanh_(zc[j]);
        float cn = ov * (f * creg[j] + i * ci) + (fm - ov) * creg[j] + (im - ov) * ci;
        creg[j] = cn;
        ho[j] = o * tanh_(cn);
      }
      float4 hv;
      hv.x = ho[0]; hv.y = ho[1]; hv.z = ho[2]; hv.w = ho[3];
      *(float4*)(Y + ((long)g * TT + t) * UU + lgate * 64 + c0) = hv;
      union { f16 h[4]; unsigned long long u; } pk;
      pk.h[0] = (f16)ho[0]; pk.h[1] = (f16)ho[1];
      pk.h[2] = (f16)ho[2]; pk.h[3] = (f16)ho[3];
      __hip_atomic_store(hbuf + ((g * 1024 + lgate * 64 + c0) >> 2), pk.u, __ATOMIC_RELAXED, __HIP_MEMORY_SCOPE_AGENT);
    }
    ++bar;
    grid_bar(cnt, bar);
  }
}

// ---------------- launch ----------------
extern "C" void kernel_launch(void* const* d_in, const int* in_sizes, int n_in,
                              void* d_out, int out_size, void* d_ws, size_t ws_size,
                              hipStream_t stream) {
  const float* X = (const float*)d_in[0];
  const float* W = (const float*)d_in[1];
  const float* Rm = (const float*)d_in[2];
  const float* bias = (const float*)d_in[3];
  float* Y = (float*)d_out;
  char* ws = (char*)d_ws;

  const size_t off_cnt = 0;
  const size_t off_h   = 256;                        // 64 KiB
  const size_t off_z   = 65792;                      // 528,384 B
  const size_t off_Wt  = 594176;                     // GPAD*1024*2 = 8,650,752 B
  const size_t off_Rt  = 9244928;                    // GG*1024*2  = 8,454,144 B
  const size_t off_Zx  = 17699072;                   // 16384*GG*2 = 135,266,304 B
  const size_t need = off_Zx + (size_t)16384 * GG * 2;
  if (ws_size < need) return;  // fail visibly (poisoned output), never hang

  unsigned* cnt = (unsigned*)(ws + off_cnt);
  unsigned long long* hbuf = (unsigned long long*)(ws + off_h);
  float* zbuf = (float*)(ws + off_z);
  f16* Wt = (f16*)(ws + off_Wt);
  f16* Rt = (f16*)(ws + off_Rt);
  f16* Zx = (f16*)(ws + off_Zx);

  hipMemsetAsync(ws + off_cnt, 0, 256, stream);
  hipMemsetAsync(ws + off_h, 0, 65536, stream);
  // zero the GPAD-GG pad rows of W^T so phase-1's over-read contributes 0
  hipMemsetAsync(ws + off_Wt + (size_t)GG * 1024 * 2, 0, (size_t)(GPAD - GG) * 1024 * 2, stream);

  k_transpose_cvt<<<dim3(129, 32), 256, 0, stream>>>(W, Wt, 1024, GG);
  k_transpose_cvt<<<dim3(129, 32), 256, 0, stream>>>(Rm, Rt, 1024, GG);
  k_gemm_xw<<<dim3(128, 33), 256, 0, stream>>>(X, Wt, bias, Zx);

  hipFuncSetAttribute((const void*)k_onlstm, hipFuncAttributeMaxDynamicSharedMemorySize, 131328);
  k_onlstm<<<NBLK, 256, 131328, stream>>>(Zx, Rt, hbuf, zbuf, Y, cnt);
}

// Round 2
// 6460.069 us; speedup vs baseline: 1.1233x; 1.1233x over previous
//
#include <hip/hip_runtime.h>

#define TT 512
#define GG 4128
#define GPAD 4224
#define NBLK2 32
#define NTHR2 640

typedef _Float16 f16;
typedef _Float16 half8 __attribute__((ext_vector_type(8)));
typedef _Float16 half4 __attribute__((ext_vector_type(4)));
typedef float f32x4 __attribute__((ext_vector_type(4)));
typedef unsigned long long ull;

// ---------------- transpose + f32->f16 convert: in[R][C] f32 -> out[C][R] f16 ----
__global__ void k_transpose_cvt(const float* __restrict__ in, f16* __restrict__ out,
                                int R, int C) {
  __shared__ float tile[32][33];
  int bx = blockIdx.x * 32, by = blockIdx.y * 32;
  int tx = threadIdx.x & 31, ty = threadIdx.x >> 5;
#pragma unroll
  for (int j = 0; j < 4; ++j) {
    int r = by + ty + j * 8;
    tile[ty + j * 8][tx] = in[(long)r * C + bx + tx];
  }
  __syncthreads();
#pragma unroll
  for (int j = 0; j < 4; ++j) {
    int c = bx + ty + j * 8;
    out[(long)c * R + by + tx] = (f16)tile[tx][ty + j * 8];
  }
}

// ---------------- phase 1: Z = X@W + bias, scattered into Zm / Zg layouts -------
// Zm: [t][b][32] f16   (master cols 0..31)
// Zg: [t][g][b][u5][q] f16  (gate col n = 32 + q*1024 + g*32 + u5)
__global__ __launch_bounds__(256) void k_gemm_xw(
    const float* __restrict__ X,
    const f16* __restrict__ Bt,
    const float* __restrict__ bias,
    f16* __restrict__ Zm,
    f16* __restrict__ Zg) {
  __shared__ f16 As[128 * 32];
  __shared__ f16 Bs[128 * 32];
  const int m0 = blockIdx.x * 128;
  const int n0 = blockIdx.y * 128;
  const int tid = threadIdx.x;
  const int wave = tid >> 6, lane = tid & 63;
  const int mrow = (wave & 1) * 64, ncol = (wave >> 1) * 64;
  f32x4 acc[4][4];
#pragma unroll
  for (int i = 0; i < 4; ++i)
#pragma unroll
    for (int j = 0; j < 4; ++j)
      acc[i][j] = (f32x4){0.f, 0.f, 0.f, 0.f};

  float4 ra[4];
  uint4 rb[2];
  auto load_tiles = [&](int k0) {
#pragma unroll
    for (int q = 0; q < 4; ++q) {
      int flat = q * 256 + tid;
      int r = flat >> 3, s = flat & 7;
      ra[q] = *(const float4*)(X + (long)(m0 + r) * 1024 + k0 + s * 4);
    }
#pragma unroll
    for (int q = 0; q < 2; ++q) {
      int flat = q * 256 + tid;
      int r = flat >> 2, s = flat & 3;
      rb[q] = *(const uint4*)(Bt + (long)(n0 + r) * 1024 + k0 + s * 8);
    }
  };
  load_tiles(0);
  for (int kt = 0; kt < 32; ++kt) {
    __syncthreads();
#pragma unroll
    for (int q = 0; q < 4; ++q) {
      int flat = q * 256 + tid;
      half4 h;
      h[0] = (f16)ra[q].x; h[1] = (f16)ra[q].y;
      h[2] = (f16)ra[q].z; h[3] = (f16)ra[q].w;
      *(half4*)((char*)As + flat * 8) = h;
    }
#pragma unroll
    for (int q = 0; q < 2; ++q) {
      int flat = q * 256 + tid;
      *(uint4*)((char*)Bs + flat * 16) = rb[q];
    }
    __syncthreads();
    if (kt + 1 < 32) load_tiles((kt + 1) * 32);
    const int kseg2 = ((lane >> 4) * 8) * 2;
    half8 af[4], bf[4];
#pragma unroll
    for (int i = 0; i < 4; ++i) {
      int r = mrow + i * 16 + (lane & 15);
      af[i] = *(const half8*)((const char*)As + r * 64 + kseg2);
      int c = ncol + i * 16 + (lane & 15);
      bf[i] = *(const half8*)((const char*)Bs + c * 64 + kseg2);
    }
#pragma unroll
    for (int i = 0; i < 4; ++i)
#pragma unroll
      for (int j = 0; j < 4; ++j)
        acc[i][j] = __builtin_amdgcn_mfma_f32_16x16x32_f16(af[i], bf[j], acc[i][j], 0, 0, 0);
  }
  // scatter epilogue
#pragma unroll
  for (int j = 0; j < 4; ++j) {
    int n = n0 + ncol + j * 16 + (lane & 15);
    if (n < GG) {
      float bv = bias[n];
      const int isM = (n < 32);
      int q = 0, u5 = 0, g2 = 0;
      if (!isM) {
        int k = n - 32;
        q = k >> 10;
        int u = k & 1023;
        g2 = u >> 5;
        u5 = u & 31;
      }
#pragma unroll
      for (int i = 0; i < 4; ++i) {
#pragma unroll
        for (int r = 0; r < 4; ++r) {
          int m = m0 + mrow + i * 16 + (lane >> 4) * 4 + r;
          int b = m >> 9, tt2 = m & 511;
          f16 v = (f16)(acc[i][j][r] + bv);
          if (isM)
            Zm[((long)(tt2 * 32 + b)) * 32 + n] = v;
          else
            Zg[((((long)tt2 * 32 + g2) * 32 + b) * 32 + u5) * 4 + q] = v;
        }
      }
    }
  }
}

// ---------------- phase 2 helpers ----------------
__device__ __forceinline__ float sigm(float x) { return 1.f / (1.f + __expf(-x)); }
__device__ __forceinline__ float tanh_(float x) {
  float ax = fabsf(x);
  float e = __expf(-2.f * ax);
  float t = (1.f - e) / (1.f + e);
  return copysignf(t, x);
}

// ---------------- phase 2: persistent recurrent kernel ----------------
// 32 blocks x 640 threads (10 waves). Block g owns units [g*32, g*32+32).
// Per block columns: [masters 0..31 | f | i | o | c] = 160 cols, R^T fragments
// held in registers (k-split 2: wave = colgroup*2 + khalf).
// LDS: [0,64K) h staging (swizzled); [64K, 64K+40K) z partials [2][160][32];
//       then cum[2][32] f32.
__global__ __launch_bounds__(NTHR2, 1) void k_onlstm(
    const f16* __restrict__ Zm, const f16* __restrict__ Zg,
    const f16* __restrict__ Rt, unsigned* __restrict__ hbuf,
    unsigned* __restrict__ flags, float* __restrict__ Y) {
  extern __shared__ char lds[];
  float* zp = (float*)(lds + 65536);
  float* cum = (float*)(lds + 65536 + 40960);
  const int g = blockIdx.x, tid = threadIdx.x;
  const int wave = tid >> 6, lane = tid & 63;
  const int cg = wave >> 1, kh = wave & 1;
  const int lr = lane & 15, lq = lane >> 4;

  // load B fragments (R^T) once: 2 n-tiles x 16 k-steps = 128 VGPRs
  half8 bf0[16], bf1[16];
  {
    int base = (cg == 0) ? 0 : (32 + (cg - 1) * 1024 + g * 32);
    const f16* p0 = Rt + (long)(base + lr) * 1024 + kh * 512 + lq * 8;
    const f16* p1 = Rt + (long)(base + 16 + lr) * 1024 + kh * 512 + lq * 8;
#pragma unroll
    for (int ks = 0; ks < 16; ++ks) {
      bf0[ks] = *(const half8*)(p0 + ks * 32);
      bf1[ks] = *(const half8*)(p1 + ks * 32);
    }
  }
  const bool isg = (tid >= 64 && tid < 576);
  const int gb = (tid - 64) >> 4, gu2 = (tid - 64) & 15;
  const int L0 = g >> 1;                  // all 32 units of a block share one level
  const int wb = lane & 31, wwhich = lane >> 5;
  float c0r = 0.f, c1r = 0.f;

  for (int t = 0; t < TT; ++t) {
    // --- prefetch Zx slices (plain cached loads; consumed ~1.5us later) ---
    half8 zmh0, zmh1, zxh;
    if (wave == 0) {
      const half8* zmp = (const half8*)(Zm + ((long)(t * 32 + wb) * 32 + wwhich * 16));
      zmh0 = zmp[0];
      zmh1 = zmp[1];
    }
    if (isg) {
      zxh = *(const half8*)(Zg + ((((long)t * 32 + g) * 32 + gb) * 32 + gu2 * 2) * 4);
    }
    // --- stage h(t) from global (agent-scope, L2-bypassing) into LDS ---
    const ull* hrd = (const ull*)(hbuf + (t & 1) * 16384);
#pragma unroll
    for (int it = 0; it < 13; ++it) {
      int idx = it * 640 + tid;
      if (idx < 8192) {
        ull v = __hip_atomic_load(hrd + idx, __ATOMIC_RELAXED, __HIP_MEMORY_SCOPE_AGENT);
        int b = idx >> 8, j8 = idx & 255;
        *(ull*)(lds + ((b * 128 + ((j8 >> 1) ^ (b & 7))) << 4) + (j8 & 1) * 8) = v;
      }
    }
    __syncthreads();
    // --- z = h @ R (this block's 160 cols, k-half per wave) ---
    f32x4 acc00 = {0.f, 0.f, 0.f, 0.f}, acc01 = acc00, acc10 = acc00, acc11 = acc00;
#pragma unroll
    for (int ks = 0; ks < 16; ++ks) {
      int ch = kh * 64 + ks * 4 + lq;
      half8 a0 = *(const half8*)(lds + ((lr * 128 + (ch ^ (lr & 7))) << 4));
      half8 a1 = *(const half8*)(lds + (((16 + lr) * 128 + (ch ^ ((16 + lr) & 7))) << 4));
      acc00 = __builtin_amdgcn_mfma_f32_16x16x32_f16(a0, bf0[ks], acc00, 0, 0, 0);
      acc10 = __builtin_amdgcn_mfma_f32_16x16x32_f16(a1, bf0[ks], acc10, 0, 0, 0);
      acc01 = __builtin_amdgcn_mfma_f32_16x16x32_f16(a0, bf1[ks], acc01, 0, 0, 0);
      acc11 = __builtin_amdgcn_mfma_f32_16x16x32_f16(a1, bf1[ks], acc11, 0, 0, 0);
    }
    {
      int cA = cg * 32 + lr, cB = cA + 16;
      int sA = (cA & 7) << 2, sB = (cB & 7) << 2;
      float* zA = zp + (kh * 160 + cA) * 32;
      float* zB = zp + (kh * 160 + cB) * 32;
      *(f32x4*)(zA + ((lq * 4) ^ sA)) = acc00;
      *(f32x4*)(zA + ((16 + lq * 4) ^ sA)) = acc10;
      *(f32x4*)(zB + ((lq * 4) ^ sB)) = acc01;
      *(f32x4*)(zB + ((16 + lq * 4) ^ sB)) = acc11;
    }
    __syncthreads();
    // --- masters (wave 0) || gate nonlinearities (waves 1..8) ---
    float ff[2], ii_[2], oo[2], cc[2];
    if (wave == 0) {
      float arr[16];
#pragma unroll
      for (int j = 0; j < 16; ++j) {
        int col = wwhich * 16 + j;
        int bs = wb ^ ((col & 7) << 2);
        float zm_ = (float)((j < 8) ? zmh0[j] : zmh1[j - 8]);
        arr[j] = zp[col * 32 + bs] + zp[(160 + col) * 32 + bs] + zm_;
      }
      float mx = arr[0];
#pragma unroll
      for (int j = 1; j < 16; ++j) mx = fmaxf(mx, arr[j]);
      float s = 0.f, p = 0.f;
#pragma unroll
      for (int j = 0; j < 16; ++j) {
        float e = __expf(arr[j] - mx);
        s += e;
        bool take = wwhich ? (j >= L0) : (j <= L0);
        if (take) p += e;
      }
      cum[wwhich * 32 + wb] = p / s;
    } else if (isg) {
#pragma unroll
      for (int uu = 0; uu < 2; ++uu) {
        int u5 = gu2 * 2 + uu;
        float zq[4];
#pragma unroll
        for (int q = 0; q < 4; ++q) {
          int col = 32 + q * 32 + u5;
          int bs = gb ^ ((col & 7) << 2);
          zq[q] = zp[col * 32 + bs] + zp[(160 + col) * 32 + bs] + (float)zxh[uu * 4 + q];
        }
        ff[uu] = sigm(zq[0]);
        ii_[uu] = sigm(zq[1]);
        oo[uu] = sigm(zq[2]);
        cc[uu] = tanh_(zq[3]);
      }
    }
    __syncthreads();
    // --- combine, c/h update, publish h slice ---
    if (isg) {
      float fm = cum[gb], im = cum[32 + gb];
      float ov = fm * im;
      float cn0 = ov * (ff[0] * c0r + ii_[0] * cc[0]) + (fm - ov) * c0r + (im - ov) * cc[0];
      float cn1 = ov * (ff[1] * c1r + ii_[1] * cc[1]) + (fm - ov) * c1r + (im - ov) * cc[1];
      c0r = cn0;
      c1r = cn1;
      float h0 = oo[0] * tanh_(cn0);
      float h1 = oo[1] * tanh_(cn1);
      *(float2*)(Y + (((long)gb * TT + t) << 10) + g * 32 + gu2 * 2) = make_float2(h0, h1);
      union { f16 h[2]; unsigned u; } pk;
      pk.h[0] = (f16)h0;
      pk.h[1] = (f16)h1;
      unsigned* hw = hbuf + ((t + 1) & 1) * 16384;
      __hip_atomic_store(hw + (gb * 512 + g * 16 + gu2), pk.u, __ATOMIC_RELAXED, __HIP_MEMORY_SCOPE_AGENT);
    }
    // --- single flag barrier per step ---
    asm volatile("s_waitcnt vmcnt(0)" ::: "memory");
    __syncthreads();
    if (tid == 0)
      __hip_atomic_store(flags + g * 16, (unsigned)(t + 1), __ATOMIC_RELAXED, __HIP_MEMORY_SCOPE_AGENT);
    if (wave == 0) {
      for (;;) {
        unsigned v = __hip_atomic_load(flags + (lane & 31) * 16, __ATOMIC_RELAXED, __HIP_MEMORY_SCOPE_AGENT);
        if (__all((int)(v >= (unsigned)(t + 1)))) break;
      }
    }
    __syncthreads();
  }
}

// ---------------- launch ----------------
extern "C" void kernel_launch(void* const* d_in, const int* in_sizes, int n_in,
                              void* d_out, int out_size, void* d_ws, size_t ws_size,
                              hipStream_t stream) {
  const float* X = (const float*)d_in[0];
  const float* W = (const float*)d_in[1];
  const float* Rm = (const float*)d_in[2];
  const float* bias = (const float*)d_in[3];
  float* Y = (float*)d_out;
  char* ws = (char*)d_ws;

  const size_t off_flags = 0;          // 2048 B
  const size_t off_h     = 4096;       // 131072 B (2 x 64KB h buffers)
  const size_t off_Zm    = 135168;     // 1,048,576 B
  const size_t off_Wt    = 1183744;    // 8,650,752 B (GPAD x 1024 f16)
  const size_t off_Rt    = 9834496;    // 8,454,144 B (GG x 1024 f16)
  const size_t off_Zg    = 18288640;   // 134,217,728 B
  const size_t need = off_Zg + (size_t)TT * 32 * 32 * 32 * 4 * 2;
  if (ws_size < need) return;  // fail visibly, never hang

  unsigned* flags = (unsigned*)(ws + off_flags);
  unsigned* hbuf = (unsigned*)(ws + off_h);
  f16* Zm = (f16*)(ws + off_Zm);
  f16* Wt = (f16*)(ws + off_Wt);
  f16* Rt = (f16*)(ws + off_Rt);
  f16* Zg = (f16*)(ws + off_Zg);

  hipMemsetAsync(ws + off_flags, 0, 2048, stream);
  hipMemsetAsync(ws + off_h, 0, 131072, stream);
  hipMemsetAsync(ws + off_Wt + (size_t)GG * 1024 * 2, 0, (size_t)(GPAD - GG) * 1024 * 2, stream);

  k_transpose_cvt<<<dim3(129, 32), 256, 0, stream>>>(W, Wt, 1024, GG);
  k_transpose_cvt<<<dim3(129, 32), 256, 0, stream>>>(Rm, Rt, 1024, GG);
  k_gemm_xw<<<dim3(128, 33), 256, 0, stream>>>(X, Wt, bias, Zm, Zg);

  hipFuncSetAttribute((const void*)k_onlstm, hipFuncAttributeMaxDynamicSharedMemorySize, 106752);
  k_onlstm<<<NBLK2, NTHR2, 106752, stream>>>(Zm, Zg, Rt, hbuf, flags, Y);
}

// Round 3
// 5964.417 us; speedup vs baseline: 1.2167x; 1.0831x over previous
//
#include <hip/hip_runtime.h>

#define TT 512
#define GG 4128
#define GPAD 4224
#define NBLK2 32
#define NTHR2 640

typedef _Float16 f16;
typedef _Float16 half8 __attribute__((ext_vector_type(8)));
typedef _Float16 half4 __attribute__((ext_vector_type(4)));
typedef float f32x4 __attribute__((ext_vector_type(4)));
typedef unsigned long long ull;

// ---------------- transpose + f32->f16 convert: in[R][C] f32 -> out[C][R] f16 ----
__global__ void k_transpose_cvt(const float* __restrict__ in, f16* __restrict__ out,
                                int R, int C) {
  __shared__ float tile[32][33];
  int bx = blockIdx.x * 32, by = blockIdx.y * 32;
  int tx = threadIdx.x & 31, ty = threadIdx.x >> 5;
#pragma unroll
  for (int j = 0; j < 4; ++j) {
    int r = by + ty + j * 8;
    tile[ty + j * 8][tx] = in[(long)r * C + bx + tx];
  }
  __syncthreads();
#pragma unroll
  for (int j = 0; j < 4; ++j) {
    int c = bx + ty + j * 8;
    out[(long)c * R + by + tx] = (f16)tile[tx][ty + j * 8];
  }
}

// ---------------- phase 1: Z = X@W + bias, scattered into Zm / Zg layouts -------
// Zm: [t][b][32] f16   (master cols 0..31)
// Zg: [t][g][b][u5][q] f16  (gate col n = 32 + q*1024 + g*32 + u5)
__global__ __launch_bounds__(256) void k_gemm_xw(
    const float* __restrict__ X,
    const f16* __restrict__ Bt,
    const float* __restrict__ bias,
    f16* __restrict__ Zm,
    f16* __restrict__ Zg) {
  __shared__ f16 As[128 * 32];
  __shared__ f16 Bs[128 * 32];
  const int m0 = blockIdx.x * 128;
  const int n0 = blockIdx.y * 128;
  const int tid = threadIdx.x;
  const int wave = tid >> 6, lane = tid & 63;
  const int mrow = (wave & 1) * 64, ncol = (wave >> 1) * 64;
  f32x4 acc[4][4];
#pragma unroll
  for (int i = 0; i < 4; ++i)
#pragma unroll
    for (int j = 0; j < 4; ++j)
      acc[i][j] = (f32x4){0.f, 0.f, 0.f, 0.f};

  float4 ra[4];
  uint4 rb[2];
  auto load_tiles = [&](int k0) {
#pragma unroll
    for (int q = 0; q < 4; ++q) {
      int flat = q * 256 + tid;
      int r = flat >> 3, s = flat & 7;
      ra[q] = *(const float4*)(X + (long)(m0 + r) * 1024 + k0 + s * 4);
    }
#pragma unroll
    for (int q = 0; q < 2; ++q) {
      int flat = q * 256 + tid;
      int r = flat >> 2, s = flat & 3;
      rb[q] = *(const uint4*)(Bt + (long)(n0 + r) * 1024 + k0 + s * 8);
    }
  };
  load_tiles(0);
  for (int kt = 0; kt < 32; ++kt) {
    __syncthreads();
#pragma unroll
    for (int q = 0; q < 4; ++q) {
      int flat = q * 256 + tid;
      half4 h;
      h[0] = (f16)ra[q].x; h[1] = (f16)ra[q].y;
      h[2] = (f16)ra[q].z; h[3] = (f16)ra[q].w;
      *(half4*)((char*)As + flat * 8) = h;
    }
#pragma unroll
    for (int q = 0; q < 2; ++q) {
      int flat = q * 256 + tid;
      *(uint4*)((char*)Bs + flat * 16) = rb[q];
    }
    __syncthreads();
    if (kt + 1 < 32) load_tiles((kt + 1) * 32);
    const int kseg2 = ((lane >> 4) * 8) * 2;
    half8 af[4], bf[4];
#pragma unroll
    for (int i = 0; i < 4; ++i) {
      int r = mrow + i * 16 + (lane & 15);
      af[i] = *(const half8*)((const char*)As + r * 64 + kseg2);
      int c = ncol + i * 16 + (lane & 15);
      bf[i] = *(const half8*)((const char*)Bs + c * 64 + kseg2);
    }
#pragma unroll
    for (int i = 0; i < 4; ++i)
#pragma unroll
      for (int j = 0; j < 4; ++j)
        acc[i][j] = __builtin_amdgcn_mfma_f32_16x16x32_f16(af[i], bf[j], acc[i][j], 0, 0, 0);
  }
  // scatter epilogue
#pragma unroll
  for (int j = 0; j < 4; ++j) {
    int n = n0 + ncol + j * 16 + (lane & 15);
    if (n < GG) {
      float bv = bias[n];
      const int isM = (n < 32);
      int q = 0, u5 = 0, g2 = 0;
      if (!isM) {
        int k = n - 32;
        q = k >> 10;
        int u = k & 1023;
        g2 = u >> 5;
        u5 = u & 31;
      }
#pragma unroll
      for (int i = 0; i < 4; ++i) {
#pragma unroll
        for (int r = 0; r < 4; ++r) {
          int m = m0 + mrow + i * 16 + (lane >> 4) * 4 + r;
          int b = m >> 9, tt2 = m & 511;
          f16 v = (f16)(acc[i][j][r] + bv);
          if (isM)
            Zm[((long)(tt2 * 32 + b)) * 32 + n] = v;
          else
            Zg[((((long)tt2 * 32 + g2) * 32 + b) * 32 + u5) * 4 + q] = v;
        }
      }
    }
  }
}

// ---------------- phase 2 helpers ----------------
__device__ __forceinline__ float sigm(float x) { return 1.f / (1.f + __expf(-x)); }
__device__ __forceinline__ float tanh_(float x) {
  float ax = fabsf(x);
  float e = __expf(-2.f * ax);
  float t = (1.f - e) / (1.f + e);
  return copysignf(t, x);
}

// ---------------- phase 2: persistent recurrent kernel ----------------
// 32 blocks x 640 threads (10 waves). Block g owns units [g*32, g*32+32).
// Per block columns: [masters 0..31 | f | i | o | c] = 160 cols, R^T fragments
// held in registers (k-split 2: wave = colgroup*2 + khalf).
// LDS: [0,64K) h staging (swizzled); [64K, 64K+40K) z partials [2][160][32];
//       then cum[2][32] f32.
__global__ __launch_bounds__(NTHR2, 1) void k_onlstm(
    const f16* __restrict__ Zm, const f16* __restrict__ Zg,
    const f16* __restrict__ Rt, unsigned* __restrict__ hbuf,
    unsigned* __restrict__ flags, float* __restrict__ Y) {
  extern __shared__ char lds[];
  float* zp = (float*)(lds + 65536);
  float* cum = (float*)(lds + 65536 + 40960);
  const int g = blockIdx.x, tid = threadIdx.x;
  const int wave = tid >> 6, lane = tid & 63;
  const int cg = wave >> 1, kh = wave & 1;
  const int lr = lane & 15, lq = lane >> 4;

  // load B fragments (R^T) once: 2 n-tiles x 16 k-steps = 128 VGPRs
  half8 bf0[16], bf1[16];
  {
    int base = (cg == 0) ? 0 : (32 + (cg - 1) * 1024 + g * 32);
    const f16* p0 = Rt + (long)(base + lr) * 1024 + kh * 512 + lq * 8;
    const f16* p1 = Rt + (long)(base + 16 + lr) * 1024 + kh * 512 + lq * 8;
#pragma unroll
    for (int ks = 0; ks < 16; ++ks) {
      bf0[ks] = *(const half8*)(p0 + ks * 32);
      bf1[ks] = *(const half8*)(p1 + ks * 32);
    }
  }
  const bool isg = (tid >= 64 && tid < 576);
  const int gb = (tid - 64) >> 4, gu2 = (tid - 64) & 15;
  const int L0 = g >> 1;                  // all 32 units of a block share one level
  const int wb = lane & 31, wwhich = lane >> 5;
  float c0r = 0.f, c1r = 0.f;

  for (int t = 0; t < TT; ++t) {
    // --- prefetch Zx slices (plain cached loads; consumed later) ---
    half8 zmh0, zmh1, zxh;
    if (wave == 0) {
      const half8* zmp = (const half8*)(Zm + ((long)(t * 32 + wb) * 32 + wwhich * 16));
      zmh0 = zmp[0];
      zmh1 = zmp[1];
    }
    if (isg) {
      zxh = *(const half8*)(Zg + ((((long)t * 32 + g) * 32 + gb) * 32 + gu2 * 2) * 4);
    }
    // --- stage h(t): issue ALL agent-scope loads first (one latency), then
    //     write to LDS. sched_barrier(0) keeps the scheduler from re-
    //     interleaving the dependent ds_writes between the loads, which
    //     would re-serialize into 13 IC round trips (round-2 lesson).
    const ull* hrd = (const ull*)(hbuf + (t & 1) * 16384);
    ull hv[13];
#pragma unroll
    for (int it = 0; it < 13; ++it) {
      int idx = it * 640 + tid;
      if (idx < 8192)
        hv[it] = __hip_atomic_load(hrd + idx, __ATOMIC_RELAXED, __HIP_MEMORY_SCOPE_AGENT);
    }
    __builtin_amdgcn_sched_barrier(0);
#pragma unroll
    for (int it = 0; it < 13; ++it) {
      int idx = it * 640 + tid;
      if (idx < 8192) {
        int b = idx >> 8, j8 = idx & 255;
        *(ull*)(lds + ((b * 128 + ((j8 >> 1) ^ (b & 7))) << 4) + (j8 & 1) * 8) = hv[it];
      }
    }
    __syncthreads();
    // --- z = h @ R (this block's 160 cols, k-half per wave) ---
    f32x4 acc00 = {0.f, 0.f, 0.f, 0.f}, acc01 = acc00, acc10 = acc00, acc11 = acc00;
#pragma unroll
    for (int ks = 0; ks < 16; ++ks) {
      int ch = kh * 64 + ks * 4 + lq;
      half8 a0 = *(const half8*)(lds + ((lr * 128 + (ch ^ (lr & 7))) << 4));
      half8 a1 = *(const half8*)(lds + (((16 + lr) * 128 + (ch ^ ((16 + lr) & 7))) << 4));
      acc00 = __builtin_amdgcn_mfma_f32_16x16x32_f16(a0, bf0[ks], acc00, 0, 0, 0);
      acc10 = __builtin_amdgcn_mfma_f32_16x16x32_f16(a1, bf0[ks], acc10, 0, 0, 0);
      acc01 = __builtin_amdgcn_mfma_f32_16x16x32_f16(a0, bf1[ks], acc01, 0, 0, 0);
      acc11 = __builtin_amdgcn_mfma_f32_16x16x32_f16(a1, bf1[ks], acc11, 0, 0, 0);
    }
    {
      int cA = cg * 32 + lr, cB = cA + 16;
      int sA = (cA & 7) << 2, sB = (cB & 7) << 2;
      float* zA = zp + (kh * 160 + cA) * 32;
      float* zB = zp + (kh * 160 + cB) * 32;
      *(f32x4*)(zA + ((lq * 4) ^ sA)) = acc00;
      *(f32x4*)(zA + ((16 + lq * 4) ^ sA)) = acc10;
      *(f32x4*)(zB + ((lq * 4) ^ sB)) = acc01;
      *(f32x4*)(zB + ((16 + lq * 4) ^ sB)) = acc11;
    }
    __syncthreads();
    // --- masters (wave 0) || gate nonlinearities (waves 1..8) ---
    float ff[2], ii_[2], oo[2], cc[2];
    if (wave == 0) {
      float arr[16];
#pragma unroll
      for (int j = 0; j < 16; ++j) {
        int col = wwhich * 16 + j;
        int bs = wb ^ ((col & 7) << 2);
        float zm_ = (float)((j < 8) ? zmh0[j] : zmh1[j - 8]);
        arr[j] = zp[col * 32 + bs] + zp[(160 + col) * 32 + bs] + zm_;
      }
      float mx = arr[0];
#pragma unroll
      for (int j = 1; j < 16; ++j) mx = fmaxf(mx, arr[j]);
      float s = 0.f, p = 0.f;
#pragma unroll
      for (int j = 0; j < 16; ++j) {
        float e = __expf(arr[j] - mx);
        s += e;
        bool take = wwhich ? (j >= L0) : (j <= L0);
        if (take) p += e;
      }
      cum[wwhich * 32 + wb] = p / s;
    } else if (isg) {
#pragma unroll
      for (int uu = 0; uu < 2; ++uu) {
        int u5 = gu2 * 2 + uu;
        float zq[4];
#pragma unroll
        for (int q = 0; q < 4; ++q) {
          int col = 32 + q * 32 + u5;
          int bs = gb ^ ((col & 7) << 2);
          zq[q] = zp[col * 32 + bs] + zp[(160 + col) * 32 + bs] + (float)zxh[uu * 4 + q];
        }
        ff[uu] = sigm(zq[0]);
        ii_[uu] = sigm(zq[1]);
        oo[uu] = sigm(zq[2]);
        cc[uu] = tanh_(zq[3]);
      }
    }
    __syncthreads();
    // --- combine, c/h update, publish h slice (Y store deferred off the
    //     critical path: it goes to HBM and nothing downstream reads it) ---
    float h0 = 0.f, h1 = 0.f;
    if (isg) {
      float fm = cum[gb], im = cum[32 + gb];
      float ov = fm * im;
      float cn0 = ov * (ff[0] * c0r + ii_[0] * cc[0]) + (fm - ov) * c0r + (im - ov) * cc[0];
      float cn1 = ov * (ff[1] * c1r + ii_[1] * cc[1]) + (fm - ov) * c1r + (im - ov) * cc[1];
      c0r = cn0;
      c1r = cn1;
      h0 = oo[0] * tanh_(cn0);
      h1 = oo[1] * tanh_(cn1);
      union { f16 h[2]; unsigned u; } pk;
      pk.h[0] = (f16)h0;
      pk.h[1] = (f16)h1;
      unsigned* hw = hbuf + ((t + 1) & 1) * 16384;
      __hip_atomic_store(hw + (gb * 512 + g * 16 + gu2), pk.u, __ATOMIC_RELAXED, __HIP_MEMORY_SCOPE_AGENT);
    }
    // --- single flag barrier per step (drain covers only the 4B h stores) ---
    asm volatile("s_waitcnt vmcnt(0)" ::: "memory");
    __syncthreads();
    if (tid == 0)
      __hip_atomic_store(flags + g * 16, (unsigned)(t + 1), __ATOMIC_RELAXED, __HIP_MEMORY_SCOPE_AGENT);
    if (wave == 0) {
      for (;;) {
        unsigned v = __hip_atomic_load(flags + (lane & 31) * 16, __ATOMIC_RELAXED, __HIP_MEMORY_SCOPE_AGENT);
        if (__all((int)(v >= (unsigned)(t + 1)))) break;
      }
    }
    __syncthreads();
    // deferred Y store — overlaps next step's staging; drained by next barrier
    if (isg) {
      *(float2*)(Y + (((long)gb * TT + t) << 10) + g * 32 + gu2 * 2) = make_float2(h0, h1);
    }
  }
}

// ---------------- launch ----------------
extern "C" void kernel_launch(void* const* d_in, const int* in_sizes, int n_in,
                              void* d_out, int out_size, void* d_ws, size_t ws_size,
                              hipStream_t stream) {
  const float* X = (const float*)d_in[0];
  const float* W = (const float*)d_in[1];
  const float* Rm = (const float*)d_in[2];
  const float* bias = (const float*)d_in[3];
  float* Y = (float*)d_out;
  char* ws = (char*)d_ws;

  const size_t off_flags = 0;          // 2048 B
  const size_t off_h     = 4096;       // 131072 B (2 x 64KB h buffers)
  const size_t off_Zm    = 135168;     // 1,048,576 B
  const size_t off_Wt    = 1183744;    // 8,650,752 B (GPAD x 1024 f16)
  const size_t off_Rt    = 9834496;    // 8,454,144 B (GG x 1024 f16)
  const size_t off_Zg    = 18288640;   // 134,217,728 B
  const size_t need = off_Zg + (size_t)TT * 32 * 32 * 32 * 4 * 2;
  if (ws_size < need) return;  // fail visibly, never hang

  unsigned* flags = (unsigned*)(ws + off_flags);
  unsigned* hbuf = (unsigned*)(ws + off_h);
  f16* Zm = (f16*)(ws + off_Zm);
  f16* Wt = (f16*)(ws + off_Wt);
  f16* Rt = (f16*)(ws + off_Rt);
  f16* Zg = (f16*)(ws + off_Zg);

  hipMemsetAsync(ws + off_flags, 0, 2048, stream);
  hipMemsetAsync(ws + off_h, 0, 131072, stream);
  hipMemsetAsync(ws + off_Wt + (size_t)GG * 1024 * 2, 0, (size_t)(GPAD - GG) * 1024 * 2, stream);

  k_transpose_cvt<<<dim3(129, 32), 256, 0, stream>>>(W, Wt, 1024, GG);
  k_transpose_cvt<<<dim3(129, 32), 256, 0, stream>>>(Rm, Rt, 1024, GG);
  k_gemm_xw<<<dim3(128, 33), 256, 0, stream>>>(X, Wt, bias, Zm, Zg);

  hipFuncSetAttribute((const void*)k_onlstm, hipFuncAttributeMaxDynamicSharedMemorySize, 106752);
  k_onlstm<<<NBLK2, NTHR2, 106752, stream>>>(Zm, Zg, Rt, hbuf, flags, Y);
}

// Round 4
// 3669.278 us; speedup vs baseline: 1.9777x; 1.6255x over previous
//
#include <hip/hip_runtime.h>

#define TT 512
#define GG 4128
#define GPAD 4224
#define NGATE 64
#define NMST 4
#define NBLK (NGATE + NMST)
#define NTHR 512

typedef _Float16 f16;
typedef _Float16 half8 __attribute__((ext_vector_type(8)));
typedef _Float16 half4 __attribute__((ext_vector_type(4)));
typedef float f32x4 __attribute__((ext_vector_type(4)));
typedef unsigned long long ull;

__device__ __forceinline__ half8 h8(uint4 v) {
  union { uint4 u; half8 h; } c; c.u = v; return c.h;
}

// ---------------- transpose + f32->f16 convert: in[R][C] f32 -> out[C][R] f16 ----
__global__ void k_transpose_cvt(const float* __restrict__ in, f16* __restrict__ out,
                                int R, int C) {
  __shared__ float tile[32][33];
  int bx = blockIdx.x * 32, by = blockIdx.y * 32;
  int tx = threadIdx.x & 31, ty = threadIdx.x >> 5;
#pragma unroll
  for (int j = 0; j < 4; ++j) {
    int r = by + ty + j * 8;
    tile[ty + j * 8][tx] = in[(long)r * C + bx + tx];
  }
  __syncthreads();
#pragma unroll
  for (int j = 0; j < 4; ++j) {
    int c = bx + ty + j * 8;
    out[(long)c * R + by + tx] = (f16)tile[tx][ty + j * 8];
  }
}

// ---------------- phase 1: Z = X@W + bias, scattered into Zm / Zg layouts -------
// Zm: [t][b][32] f16   (master cols 0..31)
// Zg: [t][g 64][b 32][u 16][q 4] f16  (gate col n = 32 + q*1024 + g*16 + u)
__global__ __launch_bounds__(256) void k_gemm_xw(
    const float* __restrict__ X,
    const f16* __restrict__ Bt,
    const float* __restrict__ bias,
    f16* __restrict__ Zm,
    f16* __restrict__ Zg) {
  __shared__ f16 As[128 * 32];
  __shared__ f16 Bs[128 * 32];
  const int m0 = blockIdx.x * 128;
  const int n0 = blockIdx.y * 128;
  const int tid = threadIdx.x;
  const int wave = tid >> 6, lane = tid & 63;
  const int mrow = (wave & 1) * 64, ncol = (wave >> 1) * 64;
  f32x4 acc[4][4];
#pragma unroll
  for (int i = 0; i < 4; ++i)
#pragma unroll
    for (int j = 0; j < 4; ++j)
      acc[i][j] = (f32x4){0.f, 0.f, 0.f, 0.f};

  float4 ra[4];
  uint4 rb[2];
  auto load_tiles = [&](int k0) {
#pragma unroll
    for (int q = 0; q < 4; ++q) {
      int flat = q * 256 + tid;
      int r = flat >> 3, s = flat & 7;
      ra[q] = *(const float4*)(X + (long)(m0 + r) * 1024 + k0 + s * 4);
    }
#pragma unroll
    for (int q = 0; q < 2; ++q) {
      int flat = q * 256 + tid;
      int r = flat >> 2, s = flat & 3;
      rb[q] = *(const uint4*)(Bt + (long)(n0 + r) * 1024 + k0 + s * 8);
    }
  };
  load_tiles(0);
  for (int kt = 0; kt < 32; ++kt) {
    __syncthreads();
#pragma unroll
    for (int q = 0; q < 4; ++q) {
      int flat = q * 256 + tid;
      half4 h;
      h[0] = (f16)ra[q].x; h[1] = (f16)ra[q].y;
      h[2] = (f16)ra[q].z; h[3] = (f16)ra[q].w;
      *(half4*)((char*)As + flat * 8) = h;
    }
#pragma unroll
    for (int q = 0; q < 2; ++q) {
      int flat = q * 256 + tid;
      *(uint4*)((char*)Bs + flat * 16) = rb[q];
    }
    __syncthreads();
    if (kt + 1 < 32) load_tiles((kt + 1) * 32);
    const int kseg2 = ((lane >> 4) * 8) * 2;
    half8 af[4], bf[4];
#pragma unroll
    for (int i = 0; i < 4; ++i) {
      int r = mrow + i * 16 + (lane & 15);
      af[i] = *(const half8*)((const char*)As + r * 64 + kseg2);
      int c = ncol + i * 16 + (lane & 15);
      bf[i] = *(const half8*)((const char*)Bs + c * 64 + kseg2);
    }
#pragma unroll
    for (int i = 0; i < 4; ++i)
#pragma unroll
      for (int j = 0; j < 4; ++j)
        acc[i][j] = __builtin_amdgcn_mfma_f32_16x16x32_f16(af[i], bf[j], acc[i][j], 0, 0, 0);
  }
  // scatter epilogue
#pragma unroll
  for (int j = 0; j < 4; ++j) {
    int n = n0 + ncol + j * 16 + (lane & 15);
    if (n < GG) {
      float bv = bias[n];
      const int isM = (n < 32);
      int q = 0, u4 = 0, g2 = 0;
      if (!isM) {
        int k = n - 32;
        q = k >> 10;
        int u = k & 1023;
        g2 = u >> 4;
        u4 = u & 15;
      }
#pragma unroll
      for (int i = 0; i < 4; ++i) {
#pragma unroll
        for (int r = 0; r < 4; ++r) {
          int m = m0 + mrow + i * 16 + (lane >> 4) * 4 + r;
          int b = m >> 9, tt2 = m & 511;
          f16 v = (f16)(acc[i][j][r] + bv);
          if (isM)
            Zm[((long)(tt2 * 32 + b)) * 32 + n] = v;
          else
            Zg[((((long)tt2 * 64 + g2) * 32 + b) * 16 + u4) * 4 + q] = v;
        }
      }
    }
  }
}

// ---------------- phase 2 helpers ----------------
__device__ __forceinline__ float sigm(float x) { return 1.f / (1.f + __expf(-x)); }
__device__ __forceinline__ float tanh_(float x) {
  float ax = fabsf(x);
  float e = __expf(-2.f * ax);
  float t = (1.f - e) / (1.f + e);
  return copysignf(t, x);
}
#define AG_LD(p) __hip_atomic_load((p), __ATOMIC_RELAXED, __HIP_MEMORY_SCOPE_AGENT)
#define AG_ST(p, v) __hip_atomic_store((p), (v), __ATOMIC_RELAXED, __HIP_MEMORY_SCOPE_AGENT)

// barrier with only-LDS drain (vmem stays in flight)
__device__ __forceinline__ void bar_lds() {
  asm volatile("s_waitcnt lgkmcnt(0)" ::: "memory");
  __builtin_amdgcn_sched_barrier(0);
  __builtin_amdgcn_s_barrier();
}

// ---------------- phase 2: persistent recurrent kernel ----------------
// 64 gate blocks (16 units each, 8 waves, ksplit-8, B pinned in 64 VGPRs)
// + 4 master blocks (32 master cols + cumsoftmax, broadcast via IC + mflag).
// LDS gate: [0,64K) h staging (swizzled) | [64K,128K) zp[8][4][16][32] f32
// LDS mst : [0,64K) h staging | [64K,80K) zp_m[4][32][32] | [80K,84K) zr[32][32]
__global__ __launch_bounds__(NTHR, 2) void k_onlstm(
    const f16* __restrict__ Zm, const f16* __restrict__ Zg,
    const f16* __restrict__ Rt, unsigned* __restrict__ hbuf,
    float* __restrict__ cumbuf, unsigned* __restrict__ flags,
    unsigned* __restrict__ mflags, float* __restrict__ Y) {
  extern __shared__ char lds[];
  const int g = blockIdx.x, tid = threadIdx.x;
  const int wave = tid >> 6, lane = tid & 63;
  const int lr = lane & 15, lq = lane >> 4;

  if (g < NGATE) {
    // ================= gate block =================
    const int kq = wave;               // k-slice 0..7 (K=128 each)
    const int b = tid >> 4;            // batch 0..31 (combine role)
    const int u = tid & 15;            // unit-in-block 0..15
    const int L0 = g >> 2;             // level of this block's units
    // pinned B fragments: 4 q-tiles x 4 ks, col=lr, kseg=lq
    uint4 bq[16];
    {
      const f16* base = Rt + (long)kq * 128 + lq * 8;
#pragma unroll
      for (int q = 0; q < 4; ++q)
#pragma unroll
        for (int ks = 0; ks < 4; ++ks)
          bq[q * 4 + ks] = *(const uint4*)(base + (long)(32 + q * 1024 + g * 16 + lr) * 1024 + ks * 32);
#pragma unroll
      for (int i = 0; i < 16; ++i)
        asm volatile("" : "+v"(bq[i].x), "+v"(bq[i].y), "+v"(bq[i].z), "+v"(bq[i].w));
    }
    float creg = 0.f;

    for (int t = 0; t < TT; ++t) {
      if (t > 0) {
        for (;;) {
          unsigned v = AG_LD(flags + lane * 16);
          if (__all((int)(v >= (unsigned)t))) break;
        }
      }
      // Zx prefetch (plain cached; consumed in combine)
      half4 zxh = *(const half4*)(Zg + ((((long)t * 64 + g) * 32 + b) * 16 + u) * 4);
      // stage h(t): issue all loads, then all LDS writes
      const ull* hrd = (const ull*)hbuf + (t & 1) * 8192;
      ull hv[16];
#pragma unroll
      for (int it = 0; it < 16; ++it)
        hv[it] = AG_LD(hrd + it * 512 + tid);
      __builtin_amdgcn_sched_barrier(0);
#pragma unroll
      for (int it = 0; it < 16; ++it) {
        int idx = it * 512 + tid;
        int bb = idx >> 8, j8 = idx & 255;
        *(ull*)(lds + ((bb * 128 + ((j8 >> 1) ^ (bb & 7))) << 4) + (j8 & 1) * 8) = hv[it];
      }
      bar_lds();
      // GEMM: z partial (K=128 slice kq) for 4 q-tiles x 2 batch-tiles
      f32x4 acc[4][2];
#pragma unroll
      for (int q = 0; q < 4; ++q) {
        acc[q][0] = (f32x4){0.f, 0.f, 0.f, 0.f};
        acc[q][1] = (f32x4){0.f, 0.f, 0.f, 0.f};
      }
#pragma unroll
      for (int ks = 0; ks < 4; ++ks) {
        int ch = kq * 16 + ks * 4 + lq;
        half8 a0 = *(const half8*)(lds + ((lr * 128 + (ch ^ (lr & 7))) << 4));
        half8 a1 = *(const half8*)(lds + (((16 + lr) * 128 + (ch ^ ((16 + lr) & 7))) << 4));
#pragma unroll
        for (int q = 0; q < 4; ++q) {
          acc[q][0] = __builtin_amdgcn_mfma_f32_16x16x32_f16(a0, h8(bq[q * 4 + ks]), acc[q][0], 0, 0, 0);
          acc[q][1] = __builtin_amdgcn_mfma_f32_16x16x32_f16(a1, h8(bq[q * 4 + ks]), acc[q][1], 0, 0, 0);
        }
      }
      // zp[kq][q][u=lr][b swizzled]
#pragma unroll
      for (int q = 0; q < 4; ++q)
#pragma unroll
        for (int bt = 0; bt < 2; ++bt) {
          int bsw = (bt * 16 + lq * 4) ^ ((lr & 7) << 2);
          *(f32x4*)(lds + 65536 + (((kq * 64 + q * 16 + lr) * 32 + bsw) << 2)) = acc[q][bt];
        }
      bar_lds();
      // masters ready? (usually yes — overlapped with our GEMM)
      for (;;) {
        unsigned v = AG_LD(mflags + (lane & 3) * 16);
        if (__all((int)(v >= (unsigned)(t + 1)))) break;
      }
      unsigned fmu = AG_LD((unsigned*)cumbuf + b * 32 + L0);
      unsigned imu = AG_LD((unsigned*)cumbuf + b * 32 + 16 + L0);
      // reduce 8 k-partials per gate quadrant, add Zx, activate
      float z[4];
#pragma unroll
      for (int q = 0; q < 4; ++q) {
        float s = 0.f;
        int bsw = b ^ ((u & 7) << 2);
#pragma unroll
        for (int k8 = 0; k8 < 8; ++k8)
          s += *(const float*)(lds + 65536 + (((k8 * 64 + q * 16 + u) * 32 + bsw) << 2));
        z[q] = s + (float)zxh[q];
      }
      float f = sigm(z[0]), i_ = sigm(z[1]), o = sigm(z[2]);
      float ci = tanh_(z[3]);
      float fm = __uint_as_float(fmu), im = __uint_as_float(imu);
      float ov = fm * im;
      float cn = ov * (f * creg + i_ * ci) + (fm - ov) * creg + (im - ov) * ci;
      creg = cn;
      float hval = o * tanh_(cn);
      // publish h (pack 2 units -> 4B via shfl)
      float hp = __shfl_xor(hval, 1);
      if (!(u & 1)) {
        union { f16 h[2]; unsigned w; } pk;
        pk.h[0] = (f16)hval;
        pk.h[1] = (f16)hp;
        AG_ST(hbuf + ((t + 1) & 1) * 16384 + b * 512 + g * 8 + (u >> 1), pk.w);
      }
      asm volatile("s_waitcnt vmcnt(0)" ::: "memory");
      __builtin_amdgcn_s_barrier();
      if (tid == 0) AG_ST(flags + g * 16, (unsigned)(t + 1));
      // deferred HBM store of the output (never read back)
      Y[((long)b * TT + t) * 1024 + g * 16 + u] = hval;
    }
  } else {
    // ================= master block =================
    const int mid = g - NGATE;
    const int ct = wave & 1, kq4 = wave >> 1;   // coltile, k-quarter (K=256)
    const int colm = ct * 16 + lr;
    uint4 bm[8];
    {
      const f16* pm = Rt + (long)colm * 1024 + kq4 * 256 + lq * 8;
#pragma unroll
      for (int ks = 0; ks < 8; ++ks) bm[ks] = *(const uint4*)(pm + ks * 32);
#pragma unroll
      for (int i = 0; i < 8; ++i)
        asm volatile("" : "+v"(bm[i].x), "+v"(bm[i].y), "+v"(bm[i].z), "+v"(bm[i].w));
    }
    const int rb_ = tid & 31, rc = tid >> 5;     // reduce role: (c, c+16) x b
    const int sb = tid >> 4, sl = tid & 15;      // softmax role: batch x level
    float* zpm = (float*)(lds + 65536);
    float* zr = (float*)(lds + 65536 + 16384);

    for (int t = 0; t < TT; ++t) {
      if (t > 0) {
        for (;;) {
          unsigned v = AG_LD(flags + lane * 16);
          if (__all((int)(v >= (unsigned)t))) break;
        }
      }
      // Zm prefetch for reduce role
      f16 zm0 = Zm[((long)t * 32 + rb_) * 32 + rc];
      f16 zm1 = Zm[((long)t * 32 + rb_) * 32 + rc + 16];
      // stage h(t)
      const ull* hrd = (const ull*)hbuf + (t & 1) * 8192;
      ull hv[16];
#pragma unroll
      for (int it = 0; it < 16; ++it)
        hv[it] = AG_LD(hrd + it * 512 + tid);
      __builtin_amdgcn_sched_barrier(0);
#pragma unroll
      for (int it = 0; it < 16; ++it) {
        int idx = it * 512 + tid;
        int bb = idx >> 8, j8 = idx & 255;
        *(ull*)(lds + ((bb * 128 + ((j8 >> 1) ^ (bb & 7))) << 4) + (j8 & 1) * 8) = hv[it];
      }
      bar_lds();
      // masters GEMM: 1 coltile x K=256
      f32x4 am0 = (f32x4){0.f, 0.f, 0.f, 0.f}, am1 = am0;
#pragma unroll
      for (int ks = 0; ks < 8; ++ks) {
        int ch = kq4 * 32 + ks * 4 + lq;
        half8 a0 = *(const half8*)(lds + ((lr * 128 + (ch ^ (lr & 7))) << 4));
        half8 a1 = *(const half8*)(lds + (((16 + lr) * 128 + (ch ^ ((16 + lr) & 7))) << 4));
        am0 = __builtin_amdgcn_mfma_f32_16x16x32_f16(a0, h8(bm[ks]), am0, 0, 0, 0);
        am1 = __builtin_amdgcn_mfma_f32_16x16x32_f16(a1, h8(bm[ks]), am1, 0, 0, 0);
      }
      {
        int bsw0 = (lq * 4) ^ ((colm & 7) << 2);
        int bsw1 = (16 + lq * 4) ^ ((colm & 7) << 2);
        *(f32x4*)((char*)zpm + (((kq4 * 32 + colm) * 32 + bsw0) << 2)) = am0;
        *(f32x4*)((char*)zpm + (((kq4 * 32 + colm) * 32 + bsw1) << 2)) = am1;
      }
      bar_lds();
      // reduce 4 partials + Zm -> zr
#pragma unroll
      for (int rep = 0; rep < 2; ++rep) {
        int c = rc + rep * 16;
        int bsw = rb_ ^ ((c & 7) << 2);
        float s = 0.f;
#pragma unroll
        for (int k4 = 0; k4 < 4; ++k4) s += zpm[(k4 * 32 + c) * 32 + bsw];
        s += (float)(rep ? zm1 : zm0);
        zr[c * 32 + bsw] = s;
      }
      bar_lds();
      // cumsoftmax per (batch sb, level sl)
      float vf[16], vi[16];
#pragma unroll
      for (int j = 0; j < 16; ++j) {
        vf[j] = zr[j * 32 + (sb ^ ((j & 7) << 2))];
        vi[j] = zr[(j + 16) * 32 + (sb ^ ((j & 7) << 2))];
      }
      float mf = vf[0], mi = vi[0];
#pragma unroll
      for (int j = 1; j < 16; ++j) { mf = fmaxf(mf, vf[j]); mi = fmaxf(mi, vi[j]); }
      float sf = 0.f, pf = 0.f, si = 0.f, pi = 0.f;
#pragma unroll
      for (int j = 0; j < 16; ++j) {
        float ef = __expf(vf[j] - mf);
        sf += ef;
        if (j <= sl) pf += ef;
        float ei = __expf(vi[j] - mi);
        si += ei;
        if (j >= sl) pi += ei;
      }
      if ((sb >> 3) == mid) {
        AG_ST((unsigned*)cumbuf + sb * 32 + sl, __float_as_uint(pf / sf));
        AG_ST((unsigned*)cumbuf + sb * 32 + 16 + sl, __float_as_uint(pi / si));
      }
      asm volatile("s_waitcnt vmcnt(0)" ::: "memory");
      __builtin_amdgcn_s_barrier();
      if (tid == 0) AG_ST(mflags + mid * 16, (unsigned)(t + 1));
    }
  }
}

// ---------------- launch ----------------
extern "C" void kernel_launch(void* const* d_in, const int* in_sizes, int n_in,
                              void* d_out, int out_size, void* d_ws, size_t ws_size,
                              hipStream_t stream) {
  const float* X = (const float*)d_in[0];
  const float* W = (const float*)d_in[1];
  const float* Rm = (const float*)d_in[2];
  const float* bias = (const float*)d_in[3];
  float* Y = (float*)d_out;
  char* ws = (char*)d_ws;

  const size_t off_flags = 0;           // 4096 B (64 flags x 64B)
  const size_t off_mflags = 4096;       // 1024 B
  const size_t off_cum = 8192;          // 4096 B
  const size_t off_h = 16384;           // 131072 B (2 x 64KB h buffers, f16)
  const size_t off_Zm = 147456;         // 1,048,576 B
  const size_t off_Wt = 1196032;        // 8,650,752 B (GPAD x 1024 f16)
  const size_t off_Rt = 9846784;        // 8,454,144 B (GG x 1024 f16)
  const size_t off_Zg = 18300928;       // 134,217,728 B
  const size_t need = off_Zg + (size_t)TT * 64 * 32 * 16 * 4 * 2;
  if (ws_size < need) return;  // fail visibly, never hang

  unsigned* flags = (unsigned*)(ws + off_flags);
  unsigned* mflags = (unsigned*)(ws + off_mflags);
  float* cumbuf = (float*)(ws + off_cum);
  unsigned* hbuf = (unsigned*)(ws + off_h);
  f16* Zm = (f16*)(ws + off_Zm);
  f16* Wt = (f16*)(ws + off_Wt);
  f16* Rt = (f16*)(ws + off_Rt);
  f16* Zg = (f16*)(ws + off_Zg);

  hipMemsetAsync(ws, 0, off_h + 131072, stream);  // flags+mflags+cum+hbuf
  hipMemsetAsync(ws + off_Wt + (size_t)GG * 1024 * 2, 0, (size_t)(GPAD - GG) * 1024 * 2, stream);

  k_transpose_cvt<<<dim3(129, 32), 256, 0, stream>>>(W, Wt, 1024, GG);
  k_transpose_cvt<<<dim3(129, 32), 256, 0, stream>>>(Rm, Rt, 1024, GG);
  k_gemm_xw<<<dim3(128, 33), 256, 0, stream>>>(X, Wt, bias, Zm, Zg);

  hipFuncSetAttribute((const void*)k_onlstm, hipFuncAttributeMaxDynamicSharedMemorySize, 131072);
  k_onlstm<<<NBLK, NTHR, 131072, stream>>>(Zm, Zg, Rt, hbuf, cumbuf, flags, mflags, Y);
}